// Round 2
// baseline (58032.410 us; speedup 1.0000x reference)
//
#include <hip/hip_runtime.h>

#define T_   256
#define B_   64
#define H_   1024
#define Hh_  512
#define L_   2
#define K1_  1536
#define MAXF 0.875f
#define NBLK 128
#define NT   1024

// ---- ws float offsets ----
#define OFF_WZR1 0u          // [2][64 blk][1536][16]
#define OFF_WG1  3145728u    // [2][64 blk][1536][8]
#define OFF_WZR2 4718592u
#define OFF_WG2  7864320u
#define OFF_XT   9437184u    // [2 buf][1024 k][64 r]
#define OFF_HT   9568256u    // [2 l][2 buf][1024 n][64 r]
#define OFF_ZT   9830400u    // [2 l][512 n][64 r]
#define OFF_RHT  9895936u    // [2 l][512 n][64 r]
#define OFF_CTR  9961472u    // grid barrier counter (u32[32])
#define OFF_GCNT 9961504u    // per-(xcd,layer) member count (u32[32])
#define OFF_XBAR 9961536u    // per-(xcd,layer) barrier counters (u32[32])
#define OFF_SCR  9961600u    // [8 xcd][2 l][1536 k][64 r] staged A panels

// Retile: src [L][K1][N] -> dst [L][N/C blocks][K1][C]
__global__ __launch_bounds__(256) void retile_w(const float* __restrict__ src,
                                                float* __restrict__ dst,
                                                int N, int C) {
    size_t tid = (size_t)blockIdx.x * 256 + threadIdx.x;
    size_t total = (size_t)L_ * K1_ * N;
    if (tid >= total) return;
    int c = (int)(tid % C);
    int k = (int)((tid / C) % K1_);
    int b = (int)((tid / ((size_t)C * K1_)) % (N / C));
    int l = (int)(tid / ((size_t)C * K1_ * (N / C)));
    dst[tid] = src[((size_t)l * K1_ + k) * N + b * C + c];
}

// Device-coherent (cross-XCD) access: LLC-direct, no fences needed (round-0
// semantics — the fence experiment of round 1 regressed and is reverted).
__device__ __forceinline__ float ld_coh(const float* p) {
    return __hip_atomic_load(p, __ATOMIC_RELAXED, __HIP_MEMORY_SCOPE_AGENT);
}
__device__ __forceinline__ void st_coh(float* p, float v) {
    __hip_atomic_store(p, v, __ATOMIC_RELAXED, __HIP_MEMORY_SCOPE_AGENT);
}

__device__ __forceinline__ int xcc_id() {
    int x;
    asm volatile("s_getreg_b32 %0, hwreg(HW_REG_XCC_ID)" : "=s"(x));
    return x & 7;
}

// Fence-free grid barrier (round-0): __syncthreads drains vmcnt (write-through
// stores visible at their coherence point); monotonic counter, no reset.
__device__ __forceinline__ void gbar(unsigned* ctr, unsigned* target) {
    *target += NBLK;
    __syncthreads();
    if (threadIdx.x == 0) {
        __hip_atomic_fetch_add(ctr, 1u, __ATOMIC_RELAXED, __HIP_MEMORY_SCOPE_AGENT);
        while (__hip_atomic_load(ctr, __ATOMIC_RELAXED, __HIP_MEMORY_SCOPE_AGENT) < *target)
            __builtin_amdgcn_s_sleep(1);
    }
    __syncthreads();
}

// Intra-(xcd,layer) group barrier. Counter lives in the coherent region
// (agent-scope RMW at LLC) — low contention (<=16 members), ~1 us.
__device__ __forceinline__ void xgbar(unsigned* xctr, unsigned* xtarget, int gcount) {
    *xtarget += (unsigned)gcount;
    __syncthreads();
    if (threadIdx.x == 0) {
        __hip_atomic_fetch_add(xctr, 1u, __ATOMIC_RELAXED, __HIP_MEMORY_SCOPE_AGENT);
        while (__hip_atomic_load(xctr, __ATOMIC_RELAXED, __HIP_MEMORY_SCOPE_AGENT) < *xtarget)
            __builtin_amdgcn_s_sleep(1);
    }
    __syncthreads();
}

// Stage (a slice of) the A panel [1536 k][64 r] from the coherent buffers into
// this XCD's L2-resident scratch. Plain stores: CDNA vector L1 is write-through,
// so the data lands in this XCD's L2; __syncthreads in xgbar drains vmcnt before
// the group signal. full=true stages rows 0..1535, else only 1024..1535 (Ahi).
__device__ __forceinline__ void stage_panel(const float* __restrict__ lo,
                                            const float* __restrict__ hi,
                                            float* __restrict__ scr,
                                            int rank, int gcount, bool full) {
    const int kb   = full ? 0 : H_;
    const int rows = K1_ - kb;
    const int k0   = kb + rank * rows / gcount;
    const int k1   = kb + (rank + 1) * rows / gcount;
    for (int i = k0 * 64 + (int)threadIdx.x; i < k1 * 64; i += NT) {
        const int k = i >> 6;
        const float* sp = (k < H_) ? (lo + (size_t)k * 64)
                                   : (hi + (size_t)(k - H_) * 64);
        scr[i] = ld_coh(sp + (i & 63));
    }
}

// C[64 r][C cols] = A[64][1536] @ Wt[1536][C].  A now comes from the XCD-local
// scratch via sc0-only loads (bypass L1 to avoid stale lines, hit own XCD L2
// where the stagers' write-through stores live). 16-way K-split over waves,
// 8-deep batches. W via normal cached loads (L1/L2-hot, wave-uniform).
template<int C>
__device__ __forceinline__ float phase_gemm(const float* __restrict__ scr,
                                            const float* __restrict__ Wt,
                                            float* __restrict__ red) {
    const int tid  = threadIdx.x;
    const int lane = tid & 63;
    const int w    = __builtin_amdgcn_readfirstlane(tid >> 6);  // 0..15
    const int k0   = w * 96;
    for (int i = tid; i < 64 * (C + 1); i += NT) red[i] = 0.f;
    float acc[C];
#pragma unroll
    for (int c = 0; c < C; ++c) acc[c] = 0.f;
    __syncthreads();
#pragma unroll 1
    for (int kb = 0; kb < 96; kb += 8) {
        unsigned long long ap =
            (unsigned long long)(scr + (size_t)(k0 + kb) * 64 + lane);
        float a0, a1, a2, a3, a4, a5, a6, a7;
        asm volatile(
            "global_load_dword %0, %8, off sc0\n\t"
            "global_load_dword %1, %8, off offset:256 sc0\n\t"
            "global_load_dword %2, %8, off offset:512 sc0\n\t"
            "global_load_dword %3, %8, off offset:768 sc0\n\t"
            "global_load_dword %4, %8, off offset:1024 sc0\n\t"
            "global_load_dword %5, %8, off offset:1280 sc0\n\t"
            "global_load_dword %6, %8, off offset:1536 sc0\n\t"
            "global_load_dword %7, %8, off offset:1792 sc0\n\t"
            "s_waitcnt vmcnt(0)"
            : "=v"(a0), "=v"(a1), "=v"(a2), "=v"(a3),
              "=v"(a4), "=v"(a5), "=v"(a6), "=v"(a7)
            : "v"(ap)
            : "memory");
        const float av[8] = {a0, a1, a2, a3, a4, a5, a6, a7};
#pragma unroll
        for (int j = 0; j < 8; ++j) {
            const float* wr = Wt + (size_t)(k0 + kb + j) * C;
#pragma unroll
            for (int c = 0; c < C; ++c) acc[c] = fmaf(av[j], wr[c], acc[c]);
        }
    }
#pragma unroll
    for (int c = 0; c < C; ++c) atomicAdd(&red[lane * (C + 1) + c], acc[c]);
    __syncthreads();
    float v = 0.f;
    if (tid < 64 * C) v = red[(tid / C) * (C + 1) + (tid % C)];
    return v;
}

__global__ __launch_bounds__(NT) void revgru_main(
    const int* __restrict__ seq, const float* __restrict__ h0,
    const float* __restrict__ emb,
    const float* __restrict__ bzr1, const float* __restrict__ bg1,
    const float* __restrict__ bzr2, const float* __restrict__ bg2,
    float* __restrict__ ws, float* __restrict__ out)
{
    const int bi = blockIdx.x, tid = threadIdx.x;
    const int l = (bi >= 64) ? 1 : 0, bl = bi & 63;
    __shared__ float red[64 * 17];
    __shared__ int s_xcd, s_rank, s_gcnt;
    unsigned target = 0, xtarget = 0;

    float* xT  = ws + OFF_XT;
    float* hT  = ws + OFF_HT;
    float* zT  = ws + OFF_ZT;
    float* rhT = ws + OFF_RHT;
    unsigned* ctr  = (unsigned*)(ws + OFF_CTR);
    unsigned* gcnt = (unsigned*)(ws + OFF_GCNT);
    unsigned* xbar = (unsigned*)(ws + OFF_XBAR);

    const float* Wz1  = ws + OFF_WZR1 + ((size_t)l * 64 + bl) * K1_ * 16;
    const float* Wg1l = ws + OFF_WG1  + ((size_t)l * 64 + bl) * K1_ * 8;
    const float* Wz2  = ws + OFF_WZR2 + ((size_t)l * 64 + bl) * K1_ * 16;
    const float* Wg2l = ws + OFF_WG2  + ((size_t)l * 64 + bl) * K1_ * 8;

    // ---- register into (xcd, layer) group ----
    if (tid == 0) {
        int x = xcc_id();
        s_xcd = x;
        s_rank = (int)__hip_atomic_fetch_add(&gcnt[x * 2 + l], 1u,
                     __ATOMIC_RELAXED, __HIP_MEMORY_SCOPE_AGENT);
    }
    __syncthreads();
    const int xcd = s_xcd, rank = s_rank;
    float* scr = ws + OFF_SCR + ((size_t)xcd * 2 + l) * ((size_t)K1_ * 64);
    unsigned* xctr = &xbar[xcd * 2 + l];

    const int gtid = bi * NT + tid;            // 0..131071, one elem each
    {   // init: hT[l][buf=1] = h0^T (first step reads buf^1 = 1)
        int ll = gtid >> 16, rem = gtid & 65535, r = rem >> 10, n = rem & 1023;
        st_coh(&hT[(((size_t)ll * 2 + 1) * H_ + n) * 64 + r], h0[gtid]);
        if (bi < 64) {  // xT[0] = emb gather for t=0 (65536 elems, blocks 0..63)
            int k = gtid >> 6, rr = gtid & 63;
            st_coh(&xT[gtid], emb[(size_t)seq[rr] * H_ + k]);
        }
    }
    gbar(ctr, &target);
    if (tid == 0)
        s_gcnt = (int)__hip_atomic_load(&gcnt[xcd * 2 + l],
                     __ATOMIC_RELAXED, __HIP_MEMORY_SCOPE_AGENT);
    __syncthreads();
    const int gcount = s_gcnt;

    // Pipelined: L0 blocks process t=s, L1 blocks t=s-1.
    for (int s = 0; s <= T_; ++s) {
        const int t = (l == 0) ? s : s - 1;
        const bool act = (t >= 0) && (t < T_);
        const int buf = t & 1;
        float* hC = hT + ((size_t)l * 2 + buf) * (H_ * 64);        // new state
        float* hP = hT + ((size_t)l * 2 + (buf ^ 1)) * (H_ * 64);  // old state
        const float* Ax = (l == 0) ? (xT + (size_t)buf * (H_ * 64))
                                   : (hT + (size_t)buf * (H_ * 64));  // L0 h(t)
        float* zl  = zT  + (size_t)l * Hh_ * 64;
        float* rhl = rhT + (size_t)l * Hh_ * 64;

        // ---- P1: zr1 = [x, h2_old] @ Wzr1 ----
        if (act) stage_panel(Ax, hP + Hh_ * 64, scr, rank, gcount, true);
        xgbar(xctr, &xtarget, gcount);
        if (act) {
            float v = phase_gemm<16>(scr, Wz1, red);
            int r = tid >> 4, c = tid & 15, n = bl * 16 + c;
            v += bzr1[l * H_ + n];
            float sg = 1.f / (1.f + __expf(-v));
            if (n < Hh_) st_coh(&zl[n * 64 + r], sg * MAXF + (1.f - MAXF));
            else st_coh(&rhl[(n - Hh_) * 64 + r],
                        sg * ld_coh(&hP[(size_t)n * 64 + r]));     // r1*h2_old
            if (l == 0 && t + 1 < T_) {   // prefetch x(t+1)
                int k = gtid >> 6, rr = gtid & 63;
                st_coh(&xT[(size_t)((t + 1) & 1) * (H_ * 64) + k * 64 + rr],
                       emb[(size_t)seq[(t + 1) * B_ + rr] * H_ + k]);
            }
        }
        gbar(ctr, &target);
        // ---- P2: g1; h1_new = z1*h1_old + (1-z1)*g1 ----
        if (act) stage_panel(Ax, rhl, scr, rank, gcount, false);
        xgbar(xctr, &xtarget, gcount);
        if (act) {
            float v = phase_gemm<8>(scr, Wg1l, red);
            if (tid < 512) {
                int r = tid >> 3, c = tid & 7, n = bl * 8 + c;
                float g = tanhf(v + bg1[l * Hh_ + n]);
                float z = ld_coh(&zl[n * 64 + r]);
                float h1o = ld_coh(&hP[(size_t)n * 64 + r]);
                st_coh(&hC[(size_t)n * 64 + r], z * h1o + (1.f - z) * g);
            }
        }
        gbar(ctr, &target);
        // ---- P3: zr2 = [x, h1_new] @ Wzr2 ----
        if (act) stage_panel(Ax, hC, scr, rank, gcount, false);
        xgbar(xctr, &xtarget, gcount);
        if (act) {
            float v = phase_gemm<16>(scr, Wz2, red);
            int r = tid >> 4, c = tid & 15, n = bl * 16 + c;
            v += bzr2[l * H_ + n];
            float sg = 1.f / (1.f + __expf(-v));
            if (n < Hh_) st_coh(&zl[n * 64 + r], sg * MAXF + (1.f - MAXF));
            else st_coh(&rhl[(n - Hh_) * 64 + r],
                        sg * ld_coh(&hC[(size_t)(n - Hh_) * 64 + r])); // r2*h1n
        }
        gbar(ctr, &target);
        // ---- P4: g2; h2_new = z2*h2_old + (1-z2)*g2 ----
        if (act) stage_panel(Ax, rhl, scr, rank, gcount, false);
        xgbar(xctr, &xtarget, gcount);
        if (act) {
            float v = phase_gemm<8>(scr, Wg2l, red);
            if (tid < 512) {
                int r = tid >> 3, c = tid & 7, n = bl * 8 + c;
                float g = tanhf(v + bg2[l * Hh_ + n]);
                float z = ld_coh(&zl[n * 64 + r]);
                float h2o = ld_coh(&hP[(size_t)(Hh_ + n) * 64 + r]);
                st_coh(&hC[(size_t)(Hh_ + n) * 64 + r], z * h2o + (1.f - z) * g);
            }
        }
        gbar(ctr, &target);
    }
    {   // out[l][r][n] = hT[l][1][n][r]  (final t=255 -> buf 1 for both layers)
        int ll = gtid >> 16, rem = gtid & 65535, r = rem >> 10, n = rem & 1023;
        out[gtid] = ld_coh(&hT[(((size_t)ll * 2 + 1) * H_ + n) * 64 + r]);
    }
}

extern "C" void kernel_launch(void* const* d_in, const int* in_sizes, int n_in,
                              void* d_out, int out_size, void* d_ws, size_t ws_size,
                              hipStream_t stream) {
    (void)in_sizes; (void)n_in; (void)out_size; (void)ws_size;
    const int*   seq  = (const int*)  d_in[0];
    const float* h0   = (const float*)d_in[1];
    const float* emb  = (const float*)d_in[2];
    const float* Wzr1 = (const float*)d_in[3];
    const float* bzr1 = (const float*)d_in[4];
    const float* Wg1  = (const float*)d_in[5];
    const float* bg1  = (const float*)d_in[6];
    const float* Wzr2 = (const float*)d_in[7];
    const float* bzr2 = (const float*)d_in[8];
    const float* Wg2  = (const float*)d_in[9];
    const float* bg2  = (const float*)d_in[10];
    float* out = (float*)d_out;
    float* ws  = (float*)d_ws;

    hipMemsetAsync((char*)d_ws + (size_t)OFF_CTR * 4, 0, 512, stream);
    retile_w<<<12288, 256, 0, stream>>>(Wzr1, ws + OFF_WZR1, H_, 16);
    retile_w<<<6144,  256, 0, stream>>>(Wg1,  ws + OFF_WG1,  Hh_, 8);
    retile_w<<<12288, 256, 0, stream>>>(Wzr2, ws + OFF_WZR2, H_, 16);
    retile_w<<<6144,  256, 0, stream>>>(Wg2,  ws + OFF_WG2,  Hh_, 8);

    void* args[] = { &seq, &h0, &emb, &bzr1, &bg1, &bzr2, &bg2, &ws, &out };
    hipLaunchCooperativeKernel((void*)revgru_main, dim3(NBLK), dim3(NT),
                               args, 0, stream);
}

// Round 3
// 46993.243 us; speedup vs baseline: 1.2349x; 1.2349x over previous
//
#include <hip/hip_runtime.h>

#define T_   256
#define B_   64
#define H_   1024
#define Hh_  512
#define L_   2
#define K1_  1536
#define MAXF 0.875f
#define NBLK 256
#define NT   1024

// ---- ws float offsets ----
#define OFF_WZR1 0u          // [2][64 blk][1536][16]
#define OFF_WG1  3145728u    // [2][64 blk][1536][8]
#define OFF_WZR2 4718592u
#define OFF_WG2  7864320u
#define OFF_XT   9437184u    // [2 buf][1024 k][64 r]
#define OFF_HT   9568256u    // [2 l][2 par][1024 n][64 r]
#define OFF_ZT   9830400u    // [2 l][512 n][64 r]
#define OFF_RHT  9895936u    // [2 l][512 n][64 r]
#define OFF_XC   9961472u    // [2 l][2 par][64 blk][48 c][64 r]
#define OFF_BARS 10747904u   // u32[96]: [0:16) C0, [16:32) C1, [32:96) global

// Retile: src [L][K1][N] -> dst [L][N/C blocks][K1][C]
__global__ __launch_bounds__(256) void retile_w(const float* __restrict__ src,
                                                float* __restrict__ dst,
                                                int N, int C) {
    size_t tid = (size_t)blockIdx.x * 256 + threadIdx.x;
    size_t total = (size_t)L_ * K1_ * N;
    if (tid >= total) return;
    int c = (int)(tid % C);
    int k = (int)((tid / C) % K1_);
    int b = (int)((tid / ((size_t)C * K1_)) % (N / C));
    int l = (int)(tid / ((size_t)C * K1_ * (N / C)));
    dst[tid] = src[((size_t)l * K1_ + k) * N + b * C + c];
}

// Device-coherent (cross-XCD, MALL-direct) activation access — round-0
// semantics: no fences ever needed; __syncthreads drains vmcnt before any
// barrier arrival, and st_coh is write-through to the coherence point.
__device__ __forceinline__ float ld_coh(const float* p) {
    return __hip_atomic_load(p, __ATOMIC_RELAXED, __HIP_MEMORY_SCOPE_AGENT);
}
__device__ __forceinline__ void st_coh(float* p, float v) {
    __hip_atomic_store(p, v, __ATOMIC_RELAXED, __HIP_MEMORY_SCOPE_AGENT);
}

// Tree barrier: blocks in groups of 4 -> ncnt counters (pow2, <=64).
// Arrive: 1 RMW on own group line (4 serial RMWs max per line, vs 128 on a
// single line before). Release: wave 0 polls ALL counters in one 64-lane
// vector sweep. Monotonic counters, no reset.
__device__ __forceinline__ void tbar(unsigned* ctrs, int ncnt, int group,
                                     unsigned* round) {
    *round += 1;
    const unsigned need = 4u * *round;
    __syncthreads();
    if (threadIdx.x < 64) {
        if (threadIdx.x == 0)
            __hip_atomic_fetch_add(&ctrs[group], 1u, __ATOMIC_RELAXED,
                                   __HIP_MEMORY_SCOPE_AGENT);
        const int j = (int)threadIdx.x & (ncnt - 1);
        for (;;) {
            unsigned v = __hip_atomic_load(&ctrs[j], __ATOMIC_RELAXED,
                                           __HIP_MEMORY_SCOPE_AGENT);
            if (__all(v >= need)) break;
            __builtin_amdgcn_s_sleep(1);
        }
    }
    __syncthreads();
}

// Dependent-part GEMM: C[64 r][C c] = A[512 k][64 r]^T @ Wt[rows 1024..1535].
// 16-way K-split (32 rows/wave), single 32-deep load batch (one latency
// exposure instead of 12 serial vmcnt(0) batches). LDS-atomic reduce.
template<int C>
__device__ __forceinline__ float dep_gemm(const float* __restrict__ Apanel,
                                          const float* __restrict__ Wt,
                                          float* __restrict__ red) {
    const int tid  = threadIdx.x;
    const int lane = tid & 63;
    const int w    = __builtin_amdgcn_readfirstlane(tid >> 6);  // 0..15
    const int k0   = w * 32;
    for (int i = tid; i < 64 * (C + 1); i += NT) red[i] = 0.f;
    float av[32];
#pragma unroll
    for (int j = 0; j < 32; ++j)
        av[j] = ld_coh(Apanel + (size_t)(k0 + j) * 64 + lane);
    float acc[C];
#pragma unroll
    for (int c = 0; c < C; ++c) acc[c] = 0.f;
    __syncthreads();
#pragma unroll
    for (int j = 0; j < 32; ++j) {
        const float* wr = Wt + (size_t)(H_ + k0 + j) * C;
#pragma unroll
        for (int c = 0; c < C; ++c) acc[c] = fmaf(av[j], wr[c], acc[c]);
    }
#pragma unroll
    for (int c = 0; c < C; ++c) atomicAdd(&red[lane * (C + 1) + c], acc[c]);
    __syncthreads();
    float v = 0.f;
    if (tid < 64 * C) v = red[(tid / C) * (C + 1) + (tid % C)];
    return v;
}

// Helper GEMM: Xc[48 c][64 r] = A[1024 k][64 r]^T @ [Wz1|Wg1|Wz2|Wg2][0:1024].
// Off the critical path: runs one iteration ahead, syncs only at step bounds.
__device__ __forceinline__ void helper_gemm(const float* __restrict__ Apanel,
                                            const float* __restrict__ Wz1t,
                                            const float* __restrict__ Wg1t,
                                            const float* __restrict__ Wz2t,
                                            const float* __restrict__ Wg2t,
                                            float* __restrict__ red,
                                            float* __restrict__ XcOut) {
    const int tid  = threadIdx.x;
    const int lane = tid & 63;
    const int w    = __builtin_amdgcn_readfirstlane(tid >> 6);  // 0..15
    const int k0   = w * 64;
    for (int i = tid; i < 64 * 49; i += NT) red[i] = 0.f;
    float acc[48];
#pragma unroll
    for (int c = 0; c < 48; ++c) acc[c] = 0.f;
    __syncthreads();
#pragma unroll 1
    for (int kb = 0; kb < 64; kb += 8) {
        float av[8];
#pragma unroll
        for (int j = 0; j < 8; ++j)
            av[j] = ld_coh(Apanel + (size_t)(k0 + kb + j) * 64 + lane);
#pragma unroll
        for (int j = 0; j < 8; ++j) {
            const int k = k0 + kb + j;
            const float* w1 = Wz1t + (size_t)k * 16;
            const float* g1 = Wg1t + (size_t)k * 8;
            const float* w2 = Wz2t + (size_t)k * 16;
            const float* g2 = Wg2t + (size_t)k * 8;
#pragma unroll
            for (int c = 0; c < 16; ++c) acc[c]      = fmaf(av[j], w1[c], acc[c]);
#pragma unroll
            for (int c = 0; c < 8;  ++c) acc[16 + c] = fmaf(av[j], g1[c], acc[16 + c]);
#pragma unroll
            for (int c = 0; c < 16; ++c) acc[24 + c] = fmaf(av[j], w2[c], acc[24 + c]);
#pragma unroll
            for (int c = 0; c < 8;  ++c) acc[40 + c] = fmaf(av[j], g2[c], acc[40 + c]);
        }
    }
#pragma unroll
    for (int c = 0; c < 48; ++c) atomicAdd(&red[lane * 49 + c], acc[c]);
    __syncthreads();
    for (int i = tid; i < 48 * 64; i += NT) {
        int cs = i >> 6, r = i & 63;
        st_coh(&XcOut[(size_t)cs * 64 + r], red[r * 49 + cs]);
    }
}

// Roles: bi 0..63 = C0 (layer-0 chain), 64..127 = C1, 128..191 = H0 (helpers
// computing Xc for layer 0), 192..255 = H1. Schedule at iter s:
//   H0: Xc_L0(t=s)      C0: step t=s-1      H1: Xc_L1(t=s-2)    C1: step t=s-3
// All handoffs are parity-double-buffered and separated by the end-of-iter
// global barrier (2-deep pipeline => reader of parity p at iter s vs writer of
// parity p at iter s+1 never overlap).
__global__ __launch_bounds__(NT) void revgru_main(
    const int* __restrict__ seq, const float* __restrict__ h0,
    const float* __restrict__ emb,
    const float* __restrict__ bzr1, const float* __restrict__ bg1,
    const float* __restrict__ bzr2, const float* __restrict__ bg2,
    float* __restrict__ ws, float* __restrict__ out)
{
    const int bi = blockIdx.x, tid = threadIdx.x;
    const bool isChain = (bi < 128);
    const int l  = isChain ? (bi >> 6) : ((bi - 128) >> 6);
    const int bl = bi & 63;
    __shared__ float red[64 * 49];
    unsigned rG = 0, rC = 0;

    float* xT  = ws + OFF_XT;
    float* hT  = ws + OFF_HT;
    float* zT  = ws + OFF_ZT;
    float* rhT = ws + OFF_RHT;
    unsigned* barC0 = (unsigned*)(ws + OFF_BARS);
    unsigned* barC1 = barC0 + 16;
    unsigned* barG  = barC0 + 32;

    const float* Wz1  = ws + OFF_WZR1 + ((size_t)l * 64 + bl) * K1_ * 16;
    const float* Wg1l = ws + OFF_WG1  + ((size_t)l * 64 + bl) * K1_ * 8;
    const float* Wz2  = ws + OFF_WZR2 + ((size_t)l * 64 + bl) * K1_ * 16;
    const float* Wg2l = ws + OFF_WG2  + ((size_t)l * 64 + bl) * K1_ * 8;

    // ---- init: h0 -> hT[l][par=1] (t=0 reads par^1=1); x(0) -> xT[0] ----
    if (bi < 128) {
        int gtid = bi * NT + tid;   // 0..131071
        int ll = gtid >> 16, rem = gtid & 65535, r = rem >> 10, n = rem & 1023;
        st_coh(&hT[(((size_t)ll * 2 + 1) * H_ + n) * 64 + r], h0[gtid]);
    } else if (bi < 192) {
        int g2i = (bi - 128) * NT + tid;   // 0..65535
        int k = g2i >> 6, rr = g2i & 63;
        st_coh(&xT[(size_t)k * 64 + rr], emb[(size_t)seq[rr] * H_ + k]);
    }
    tbar(barG, 64, bi >> 2, &rG);

    for (int s = 0; s <= 258; ++s) {
        if (isChain) {
            const int t = s - 1 - 2 * l;
            if (t >= 0 && t < T_) {
                const int par = t & 1;
                float* hC = hT + ((size_t)l * 2 + par) * (H_ * 64);
                float* hP = hT + ((size_t)l * 2 + (par ^ 1)) * (H_ * 64);
                float* zl  = zT  + (size_t)l * Hh_ * 64;
                float* rhl = rhT + (size_t)l * Hh_ * 64;
                const float* Xcb = ws + OFF_XC +
                    (((size_t)l * 2 + par) * 64 + bl) * (48 * 64);
                unsigned* barC = l ? barC1 : barC0;

                // ---- P1: zr1 = Xc_zr1 + h2_old @ Wzr1[1024:] ----
                {
                    int r = tid >> 4, c = tid & 15, n = bl * 16 + c;
                    float xc = ld_coh(&Xcb[(size_t)c * 64 + r]) + bzr1[l * H_ + n];
                    float hv = ld_coh(&hP[(size_t)n * 64 + r]);   // for n>=512
                    float v = dep_gemm<16>(hP + Hh_ * 64, Wz1, red) + xc;
                    float sg = 1.f / (1.f + __expf(-v));
                    if (n < Hh_) st_coh(&zl[n * 64 + r], sg * MAXF + (1.f - MAXF));
                    else st_coh(&rhl[(n - Hh_) * 64 + r], sg * hv);  // r1*h2_old
                }
                tbar(barC, 16, bl >> 2, &rC);
                // ---- P2: g1 = tanh(Xc_g1 + rh1 @ Wg1[1024:]); h1n ----
                {
                    int tt = tid & 511, r = tt >> 3, c = tt & 7, n = bl * 8 + c;
                    float xc  = ld_coh(&Xcb[(size_t)(16 + c) * 64 + r]) + bg1[l * Hh_ + n];
                    float z   = ld_coh(&zl[n * 64 + r]);
                    float h1o = ld_coh(&hP[(size_t)n * 64 + r]);
                    float v = dep_gemm<8>(rhl, Wg1l, red);
                    if (tid < 512) {
                        float g = tanhf(v + xc);
                        st_coh(&hC[(size_t)n * 64 + r], z * h1o + (1.f - z) * g);
                    }
                }
                tbar(barC, 16, bl >> 2, &rC);
                // ---- P3: zr2 = Xc_zr2 + h1n @ Wzr2[1024:] ----
                {
                    int r = tid >> 4, c = tid & 15, n = bl * 16 + c;
                    float xc = ld_coh(&Xcb[(size_t)(24 + c) * 64 + r]) + bzr2[l * H_ + n];
                    float hv = ld_coh(&hC[(size_t)((n >= Hh_) ? (n - Hh_) : n) * 64 + r]);
                    float v = dep_gemm<16>(hC, Wz2, red) + xc;
                    float sg = 1.f / (1.f + __expf(-v));
                    if (n < Hh_) st_coh(&zl[n * 64 + r], sg * MAXF + (1.f - MAXF));
                    else st_coh(&rhl[(n - Hh_) * 64 + r], sg * hv);  // r2*h1n
                }
                tbar(barC, 16, bl >> 2, &rC);
                // ---- P4: g2 = tanh(Xc_g2 + rh2 @ Wg2[1024:]); h2n ----
                {
                    int tt = tid & 511, r = tt >> 3, c = tt & 7, n = bl * 8 + c;
                    float xc  = ld_coh(&Xcb[(size_t)(40 + c) * 64 + r]) + bg2[l * Hh_ + n];
                    float z   = ld_coh(&zl[n * 64 + r]);
                    float h2o = ld_coh(&hP[(size_t)(Hh_ + n) * 64 + r]);
                    float v = dep_gemm<8>(rhl, Wg2l, red);
                    if (tid < 512) {
                        float g = tanhf(v + xc);
                        st_coh(&hC[(size_t)(Hh_ + n) * 64 + r], z * h2o + (1.f - z) * g);
                    }
                }
            }
        } else {
            const int th = s - 2 * l;
            if (th >= 0 && th < T_) {
                const int par = th & 1;
                const float* Ap = (l == 0) ? (xT + (size_t)par * (H_ * 64))
                                           : (hT + (size_t)par * (H_ * 64)); // h_L0
                float* XcOut = ws + OFF_XC +
                    (((size_t)l * 2 + par) * 64 + bl) * (48 * 64);
                helper_gemm(Ap, Wz1, Wg1l, Wz2, Wg2l, red, XcOut);
                if (l == 0 && th + 1 < T_) {   // gather x(th+1) into other buf
                    int g2i = bl * NT + tid;
                    int k = g2i >> 6, rr = g2i & 63;
                    st_coh(&xT[(size_t)((th + 1) & 1) * (H_ * 64) + (size_t)k * 64 + rr],
                           emb[(size_t)seq[(th + 1) * B_ + rr] * H_ + k]);
                }
            }
        }
        tbar(barG, 64, bi >> 2, &rG);
    }
    {   // out[l][r][n] = hT[l][1][n][r]  (t=255 -> par 1 for both layers)
        if (bi < 128) {
            int gtid = bi * NT + tid;
            int ll = gtid >> 16, rem = gtid & 65535, r = rem >> 10, n = rem & 1023;
            out[gtid] = ld_coh(&hT[(((size_t)ll * 2 + 1) * H_ + n) * 64 + r]);
        }
    }
}

extern "C" void kernel_launch(void* const* d_in, const int* in_sizes, int n_in,
                              void* d_out, int out_size, void* d_ws, size_t ws_size,
                              hipStream_t stream) {
    (void)in_sizes; (void)n_in; (void)out_size; (void)ws_size;
    const int*   seq  = (const int*)  d_in[0];
    const float* h0   = (const float*)d_in[1];
    const float* emb  = (const float*)d_in[2];
    const float* Wzr1 = (const float*)d_in[3];
    const float* bzr1 = (const float*)d_in[4];
    const float* Wg1  = (const float*)d_in[5];
    const float* bg1  = (const float*)d_in[6];
    const float* Wzr2 = (const float*)d_in[7];
    const float* bzr2 = (const float*)d_in[8];
    const float* Wg2  = (const float*)d_in[9];
    const float* bg2  = (const float*)d_in[10];
    float* out = (float*)d_out;
    float* ws  = (float*)d_ws;

    hipMemsetAsync((char*)d_ws + (size_t)OFF_BARS * 4, 0, 512, stream);
    retile_w<<<12288, 256, 0, stream>>>(Wzr1, ws + OFF_WZR1, H_, 16);
    retile_w<<<6144,  256, 0, stream>>>(Wg1,  ws + OFF_WG1,  Hh_, 8);
    retile_w<<<12288, 256, 0, stream>>>(Wzr2, ws + OFF_WZR2, H_, 16);
    retile_w<<<6144,  256, 0, stream>>>(Wg2,  ws + OFF_WG2,  Hh_, 8);

    void* args[] = { &seq, &h0, &emb, &bzr1, &bg1, &bzr2, &bg2, &ws, &out };
    hipLaunchCooperativeKernel((void*)revgru_main, dim3(NBLK), dim3(NT),
                               args, 0, stream);
}